// Round 1
// baseline (512.721 us; speedup 1.0000x reference)
//
#include <hip/hip_runtime.h>

// Problem constants (match reference)
#define N_NODES  20000
#define N_EDGES  320000
#define E_TOT    340000      // + self loops
#define N_CAND   200000
#define IN_DIM   7
#define H1C1     256         // 4 heads * 64
#define C2       32
#define NEG_SLOPE 0.2f

// ---------------------------------------------------------------------------
// CSR build: degree histogram -> single-block scan -> scatter
// ---------------------------------------------------------------------------
__global__ void degree_kernel(const int* __restrict__ ei, int* __restrict__ deg) {
    int e = blockIdx.x * blockDim.x + threadIdx.x;
    if (e >= E_TOT) return;
    int dst = (e < N_EDGES) ? ei[N_EDGES + e] : (e - N_EDGES);
    atomicAdd(&deg[dst], 1);
}

__global__ __launch_bounds__(1024) void scan_kernel(const int* __restrict__ deg,
                                                    int* __restrict__ off,
                                                    int* __restrict__ cursor) {
    __shared__ int part[1024];
    const int t = threadIdx.x;
    const int per = (N_NODES + 1023) / 1024;   // 20
    const int start = t * per;
    const int end = min(start + per, N_NODES);
    int s = 0;
    for (int i = start; i < end; ++i) s += deg[i];
    part[t] = s;
    __syncthreads();
    // Hillis-Steele inclusive scan
    for (int d = 1; d < 1024; d <<= 1) {
        int add = (t >= d) ? part[t - d] : 0;
        __syncthreads();
        part[t] += add;
        __syncthreads();
    }
    int run = part[t] - s;   // exclusive prefix for this chunk
    for (int i = start; i < end; ++i) {
        off[i] = run;
        cursor[i] = run;
        run += deg[i];
    }
}

__global__ void scatter_kernel(const int* __restrict__ ei,
                               int* __restrict__ cursor,
                               int* __restrict__ csr_src) {
    int e = blockIdx.x * blockDim.x + threadIdx.x;
    if (e >= E_TOT) return;
    int src, dst;
    if (e < N_EDGES) { src = ei[e]; dst = ei[N_EDGES + e]; }
    else             { src = dst = e - N_EDGES; }
    int pos = atomicAdd(&cursor[dst], 1);
    csr_src[pos] = src;
}

// ---------------------------------------------------------------------------
// conv1 transform: h = x @ W1  (per-thread 7-dot), + per-(node,head) alpha
// block = 256 threads = one node; wave w == head w
// ---------------------------------------------------------------------------
__global__ __launch_bounds__(256) void transform1_kernel(
        const float* __restrict__ x, const float* __restrict__ W1,
        const float* __restrict__ a_src1, const float* __restrict__ a_dst1,
        float* __restrict__ h, float* __restrict__ als1, float* __restrict__ ald1) {
    const int v = blockIdx.x;
    const int o = threadIdx.x;           // 0..255  (= head*64 + c)
    float acc = 0.f;
#pragma unroll
    for (int k = 0; k < IN_DIM; ++k)
        acc += x[v * IN_DIM + k] * W1[k * H1C1 + o];
    h[v * H1C1 + o] = acc;

    const int head = o >> 6, lane = o & 63;
    float ps = acc * a_src1[o];          // a_src1 is (4,64) flat = [o]
    float pd = acc * a_dst1[o];
#pragma unroll
    for (int sft = 32; sft; sft >>= 1) {
        ps += __shfl_xor(ps, sft);
        pd += __shfl_xor(pd, sft);
    }
    if (lane == 0) {
        als1[v * 4 + head] = ps;
        ald1[v * 4 + head] = pd;
    }
}

// ---------------------------------------------------------------------------
// conv1 aggregation + bias + ELU.  block = 256 = one node; wave = head.
// 3 passes over in-edges: max, exp-sum, weighted accumulate.
// ---------------------------------------------------------------------------
__global__ __launch_bounds__(256) void agg1_kernel(
        const float* __restrict__ h,
        const float* __restrict__ als1, const float* __restrict__ ald1,
        const int* __restrict__ csr_src, const int* __restrict__ off,
        const int* __restrict__ deg,
        const float* __restrict__ b1, float* __restrict__ h1) {
    const int v = blockIdx.x;
    const int t = threadIdx.x;
    const int head = t >> 6, lane = t & 63;
    const int start = off[v];
    const int d = deg[v];
    const float ad = ald1[v * 4 + head];

    float m = -1e30f;
    for (int j = 0; j < d; ++j) {
        int s = csr_src[start + j];
        float e = als1[s * 4 + head] + ad;
        e = (e > 0.f) ? e : NEG_SLOPE * e;
        m = fmaxf(m, e);
    }
    float z = 0.f;
    for (int j = 0; j < d; ++j) {
        int s = csr_src[start + j];
        float e = als1[s * 4 + head] + ad;
        e = (e > 0.f) ? e : NEG_SLOPE * e;
        z += __expf(e - m);
    }
    const float inv = 1.f / (z + 1e-16f);
    float acc = 0.f;
    for (int j = 0; j < d; ++j) {
        int s = csr_src[start + j];
        float e = als1[s * 4 + head] + ad;
        e = (e > 0.f) ? e : NEG_SLOPE * e;
        float coef = __expf(e - m) * inv;
        acc += h[s * H1C1 + head * 64 + lane] * coef;
    }
    float o = acc + b1[head * 64 + lane];
    h1[v * H1C1 + head * 64 + lane] = (o > 0.f) ? o : (__expf(o) - 1.f);
}

// ---------------------------------------------------------------------------
// conv2 transform: g = h1 @ W2  + per-node alpha2
// block = 256 = one node; h1 row staged in LDS
// ---------------------------------------------------------------------------
__global__ __launch_bounds__(256) void transform2_kernel(
        const float* __restrict__ h1, const float* __restrict__ W2,
        const float* __restrict__ a_src2, const float* __restrict__ a_dst2,
        float* __restrict__ g, float* __restrict__ als2, float* __restrict__ ald2) {
    __shared__ float row[H1C1];
    __shared__ float part[256];
    const int v = blockIdx.x;
    const int t = threadIdx.x;
    row[t] = h1[v * H1C1 + t];
    __syncthreads();
    const int o = t & 31, p = t >> 5;       // p in 0..7
    float s = 0.f;
#pragma unroll
    for (int k = 0; k < 32; ++k)
        s += row[p * 32 + k] * W2[(p * 32 + k) * C2 + o];
    part[t] = s;
    __syncthreads();
    if (t < 32) {
        float tot = 0.f;
#pragma unroll
        for (int q = 0; q < 8; ++q) tot += part[q * 32 + o];
        g[v * C2 + o] = tot;
        float ps = tot * a_src2[o];
        float pd = tot * a_dst2[o];
#pragma unroll
        for (int sft = 16; sft; sft >>= 1) {
            ps += __shfl_xor(ps, sft);
            pd += __shfl_xor(pd, sft);
        }
        if (o == 0) { als2[v] = ps; ald2[v] = pd; }
    }
}

// ---------------------------------------------------------------------------
// conv2 aggregation + bias.  one wave (64 threads) per node, lanes<32 accumulate
// ---------------------------------------------------------------------------
__global__ __launch_bounds__(64) void agg2_kernel(
        const float* __restrict__ g,
        const float* __restrict__ als2, const float* __restrict__ ald2,
        const int* __restrict__ csr_src, const int* __restrict__ off,
        const int* __restrict__ deg,
        const float* __restrict__ b2, float* __restrict__ h2) {
    const int v = blockIdx.x;
    const int lane = threadIdx.x;
    const int start = off[v];
    const int d = deg[v];
    const float ad = ald2[v];

    float m = -1e30f;
    for (int j = 0; j < d; ++j) {
        int s = csr_src[start + j];
        float e = als2[s] + ad;
        e = (e > 0.f) ? e : NEG_SLOPE * e;
        m = fmaxf(m, e);
    }
    float z = 0.f;
    for (int j = 0; j < d; ++j) {
        int s = csr_src[start + j];
        float e = als2[s] + ad;
        e = (e > 0.f) ? e : NEG_SLOPE * e;
        z += __expf(e - m);
    }
    const float inv = 1.f / (z + 1e-16f);
    float acc = 0.f;
    for (int j = 0; j < d; ++j) {
        int s = csr_src[start + j];
        float e = als2[s] + ad;
        e = (e > 0.f) ? e : NEG_SLOPE * e;
        float coef = __expf(e - m) * inv;
        if (lane < 32) acc += g[s * C2 + lane] * coef;
    }
    if (lane < 32) h2[v * C2 + lane] = acc + b2[lane];
}

// ---------------------------------------------------------------------------
// link scorer: one wave per candidate pair
// ---------------------------------------------------------------------------
__global__ __launch_bounds__(256) void score_kernel(
        const float* __restrict__ h2, const int* __restrict__ cand,
        const float* __restrict__ Ws, const float* __restrict__ bs,
        float* __restrict__ out) {
    const int gid = blockIdx.x * blockDim.x + threadIdx.x;
    const int w = gid >> 6;
    const int lane = threadIdx.x & 63;
    if (w >= N_CAND) return;
    const int a = cand[2 * w];
    const int b = cand[2 * w + 1];
    float v;
    if (lane < 32) v = h2[a * C2 + lane] * Ws[lane];
    else           v = h2[b * C2 + (lane - 32)] * Ws[lane];
#pragma unroll
    for (int sft = 32; sft; sft >>= 1) v += __shfl_xor(v, sft);
    if (lane == 0) out[w] = 1.f / (1.f + __expf(-(v + bs[0])));
}

// ---------------------------------------------------------------------------
extern "C" void kernel_launch(void* const* d_in, const int* in_sizes, int n_in,
                              void* d_out, int out_size, void* d_ws, size_t ws_size,
                              hipStream_t stream) {
    const float* x        = (const float*)d_in[0];
    const int*   ei       = (const int*)  d_in[1];   // [2, N_EDGES]
    const int*   cand     = (const int*)  d_in[2];   // [N_CAND, 2]
    const float* W1       = (const float*)d_in[3];
    const float* a_src1   = (const float*)d_in[4];
    const float* a_dst1   = (const float*)d_in[5];
    const float* b1       = (const float*)d_in[6];
    const float* W2       = (const float*)d_in[7];
    const float* a_src2   = (const float*)d_in[8];
    const float* a_dst2   = (const float*)d_in[9];
    const float* b2       = (const float*)d_in[10];
    const float* Ws       = (const float*)d_in[11];
    const float* bs       = (const float*)d_in[12];
    float* out = (float*)d_out;

    // workspace carve-up (all 4-byte elements)
    float* h    = (float*)d_ws;                 // 20000*256
    float* h1v  = h    + (size_t)N_NODES * H1C1;
    float* g    = h1v  + (size_t)N_NODES * H1C1; // 20000*32
    float* h2v  = g    + (size_t)N_NODES * C2;
    float* als1 = h2v  + (size_t)N_NODES * C2;   // 20000*4
    float* ald1 = als1 + (size_t)N_NODES * 4;
    float* als2 = ald1 + (size_t)N_NODES * 4;    // 20000
    float* ald2 = als2 + N_NODES;
    int*   deg  = (int*)(ald2 + N_NODES);        // 20000
    int*   cur  = deg  + N_NODES;
    int*   off  = cur  + N_NODES;
    int*   csr  = off  + N_NODES;                // 340000

    hipMemsetAsync(deg, 0, N_NODES * sizeof(int), stream);

    const int eb = (E_TOT + 255) / 256;
    degree_kernel <<<eb, 256, 0, stream>>>(ei, deg);
    scan_kernel   <<<1, 1024, 0, stream>>>(deg, off, cur);
    scatter_kernel<<<eb, 256, 0, stream>>>(ei, cur, csr);

    transform1_kernel<<<N_NODES, 256, 0, stream>>>(x, W1, a_src1, a_dst1, h, als1, ald1);
    agg1_kernel      <<<N_NODES, 256, 0, stream>>>(h, als1, ald1, csr, off, deg, b1, h1v);
    transform2_kernel<<<N_NODES, 256, 0, stream>>>(h1v, W2, a_src2, a_dst2, g, als2, ald2);
    agg2_kernel      <<<N_NODES, 64, 0, stream>>>(g, als2, ald2, csr, off, deg, b2, h2v);

    score_kernel<<<(N_CAND * 64 + 255) / 256, 256, 0, stream>>>(h2v, cand, Ws, bs, out);
}

// Round 3
// 260.867 us; speedup vs baseline: 1.9655x; 1.9655x over previous
//
#include <hip/hip_runtime.h>

// Problem constants (match reference)
#define N_NODES  20000
#define N_EDGES  320000
#define E_TOT    340000      // + self loops
#define N_CAND   200000
#define IN_DIM   7
#define H1C1     256         // 4 heads * 64
#define C2       32
#define NEG_SLOPE 0.2f

// ---------------------------------------------------------------------------
// CSR build: degree histogram -> single-block scan -> scatter
// ---------------------------------------------------------------------------
__global__ void degree_kernel(const int* __restrict__ ei, int* __restrict__ deg) {
    int e = blockIdx.x * blockDim.x + threadIdx.x;
    if (e >= E_TOT) return;
    int dst = (e < N_EDGES) ? ei[N_EDGES + e] : (e - N_EDGES);
    atomicAdd(&deg[dst], 1);
}

__global__ __launch_bounds__(1024) void scan_kernel(const int* __restrict__ deg,
                                                    int* __restrict__ off,
                                                    int* __restrict__ cursor) {
    __shared__ int part[1024];
    const int t = threadIdx.x;
    const int per = (N_NODES + 1023) / 1024;   // 20
    const int start = t * per;
    const int end = min(start + per, N_NODES);
    int s = 0;
    for (int i = start; i < end; ++i) s += deg[i];
    part[t] = s;
    __syncthreads();
    for (int d = 1; d < 1024; d <<= 1) {
        int add = (t >= d) ? part[t - d] : 0;
        __syncthreads();
        part[t] += add;
        __syncthreads();
    }
    int run = part[t] - s;   // exclusive prefix for this chunk
    for (int i = start; i < end; ++i) {
        off[i] = run;
        cursor[i] = run;
        run += deg[i];
    }
}

__global__ void scatter_kernel(const int* __restrict__ ei,
                               int* __restrict__ cursor,
                               int* __restrict__ csr_src) {
    int e = blockIdx.x * blockDim.x + threadIdx.x;
    if (e >= E_TOT) return;
    int src, dst;
    if (e < N_EDGES) { src = ei[e]; dst = ei[N_EDGES + e]; }
    else             { src = dst = e - N_EDGES; }
    int pos = atomicAdd(&cursor[dst], 1);
    csr_src[pos] = src;
}

// ---------------------------------------------------------------------------
// prep: p1[sd][k][h] = sum_c W1[k, h*64+c] * a_{src/dst}1[h, c]   (56 floats)
// ---------------------------------------------------------------------------
__global__ __launch_bounds__(64) void prep_kernel(
        const float* __restrict__ W1,
        const float* __restrict__ a_src1, const float* __restrict__ a_dst1,
        float* __restrict__ p1) {
    int t = threadIdx.x;
    if (t < 56) {
        int sd = t / 28, rem = t % 28, k = rem >> 2, h = rem & 3;
        const float* a = sd ? a_dst1 : a_src1;
        float sum = 0.f;
        for (int c = 0; c < 64; ++c)
            sum += W1[k * H1C1 + h * 64 + c] * a[h * 64 + c];
        p1[t] = sum;   // layout [sd*28 + k*4 + h]
    }
}

// ---------------------------------------------------------------------------
// alpha1: als1[v][h] = x[v]·p_src[:,h], ald1 likewise. Thread per node.
// ---------------------------------------------------------------------------
__global__ __launch_bounds__(256) void alpha1_kernel(
        const float* __restrict__ x, const float* __restrict__ p1,
        float* __restrict__ als1, float* __restrict__ ald1) {
    int v = blockIdx.x * blockDim.x + threadIdx.x;
    if (v >= N_NODES) return;
    float xs[IN_DIM];
#pragma unroll
    for (int k = 0; k < IN_DIM; ++k) xs[k] = x[v * IN_DIM + k];
    float4 s = {0.f, 0.f, 0.f, 0.f}, d = {0.f, 0.f, 0.f, 0.f};
#pragma unroll
    for (int k = 0; k < IN_DIM; ++k) {
        float4 ps = *(const float4*)&p1[k * 4];
        float4 pd = *(const float4*)&p1[28 + k * 4];
        s.x += xs[k] * ps.x; s.y += xs[k] * ps.y; s.z += xs[k] * ps.z; s.w += xs[k] * ps.w;
        d.x += xs[k] * pd.x; d.y += xs[k] * pd.y; d.z += xs[k] * pd.z; d.w += xs[k] * pd.w;
    }
    *(float4*)&als1[v * 4] = s;
    *(float4*)&ald1[v * 4] = d;
}

// ---------------------------------------------------------------------------
// conv1 aggregation via linearity: xagg[v][h] = sum_e coef·x[src], then @W1.
// One wave per node; lane j owns edge j; online softmax across 64-edge rounds.
// ---------------------------------------------------------------------------
__global__ __launch_bounds__(64) void agg1_kernel(
        const float* __restrict__ x,
        const float* __restrict__ als1, const float* __restrict__ ald1,
        const int* __restrict__ csr_src, const int* __restrict__ off,
        const int* __restrict__ deg,
        const float* __restrict__ W1, const float* __restrict__ b1,
        float* __restrict__ h1) {
    const int v = blockIdx.x;
    const int lane = threadIdx.x;
    const int start = off[v];
    const int d = deg[v];
    const float4 adv = *(const float4*)&ald1[v * 4];
    const float ad[4] = {adv.x, adv.y, adv.z, adv.w};

    float m[4] = {-1e30f, -1e30f, -1e30f, -1e30f};
    float z[4] = {0.f, 0.f, 0.f, 0.f};
    float acc[4][IN_DIM] = {};

    for (int base = 0; base < d; base += 64) {
        const int j = base + lane;
        const bool act = (j < d);
        int s = 0;
        float e[4];
        float xs[IN_DIM];
        if (act) {
            s = csr_src[start + j];
            float4 av = *(const float4*)&als1[s * 4];
            e[0] = av.x + ad[0]; e[1] = av.y + ad[1];
            e[2] = av.z + ad[2]; e[3] = av.w + ad[3];
#pragma unroll
            for (int h = 0; h < 4; ++h) e[h] = (e[h] > 0.f) ? e[h] : NEG_SLOPE * e[h];
#pragma unroll
            for (int k = 0; k < IN_DIM; ++k) xs[k] = x[s * IN_DIM + k];
        } else {
#pragma unroll
            for (int h = 0; h < 4; ++h) e[h] = -1e30f;
#pragma unroll
            for (int k = 0; k < IN_DIM; ++k) xs[k] = 0.f;
        }
#pragma unroll
        for (int h = 0; h < 4; ++h) {
            float rm = e[h];
#pragma unroll
            for (int sft = 32; sft; sft >>= 1) rm = fmaxf(rm, __shfl_xor(rm, sft));
            float nm = fmaxf(m[h], rm);
            float scale = __expf(m[h] - nm);
            float w = __expf(e[h] - nm);
            z[h] = z[h] * scale + w;
#pragma unroll
            for (int k = 0; k < IN_DIM; ++k)
                acc[h][k] = acc[h][k] * scale + w * xs[k];
            m[h] = nm;
        }
    }
    // cross-lane reduce (butterfly broadcasts the totals to all lanes)
#pragma unroll
    for (int h = 0; h < 4; ++h) {
#pragma unroll
        for (int sft = 32; sft; sft >>= 1) z[h] += __shfl_xor(z[h], sft);
#pragma unroll
        for (int k = 0; k < IN_DIM; ++k) {
#pragma unroll
            for (int sft = 32; sft; sft >>= 1) acc[h][k] += __shfl_xor(acc[h][k], sft);
        }
    }
    // output: lane = channel within each head; out = (xagg/z)@W1 + b1, ELU
#pragma unroll
    for (int h = 0; h < 4; ++h) {
        const float inv = 1.f / (z[h] + 1e-16f);
        float o = 0.f;
#pragma unroll
        for (int k = 0; k < IN_DIM; ++k)
            o += acc[h][k] * W1[k * H1C1 + h * 64 + lane];
        o = o * inv + b1[h * 64 + lane];
        h1[v * H1C1 + h * 64 + lane] = (o > 0.f) ? o : (__expf(o) - 1.f);
    }
}

// ---------------------------------------------------------------------------
// conv2 transform: g = h1 @ W2  + per-node alpha2 (from g, 32-dot)
// ---------------------------------------------------------------------------
__global__ __launch_bounds__(256) void transform2_kernel(
        const float* __restrict__ h1, const float* __restrict__ W2,
        const float* __restrict__ a_src2, const float* __restrict__ a_dst2,
        float* __restrict__ g, float* __restrict__ als2, float* __restrict__ ald2) {
    __shared__ float row[H1C1];
    __shared__ float part[256];
    const int v = blockIdx.x;
    const int t = threadIdx.x;
    row[t] = h1[v * H1C1 + t];
    __syncthreads();
    const int o = t & 31, p = t >> 5;       // p in 0..7
    float s = 0.f;
#pragma unroll
    for (int k = 0; k < 32; ++k)
        s += row[p * 32 + k] * W2[(p * 32 + k) * C2 + o];
    part[t] = s;
    __syncthreads();
    if (t < 32) {
        float tot = 0.f;
#pragma unroll
        for (int q = 0; q < 8; ++q) tot += part[q * 32 + o];
        g[v * C2 + o] = tot;
        float ps = tot * a_src2[o];
        float pd = tot * a_dst2[o];
#pragma unroll
        for (int sft = 16; sft; sft >>= 1) {
            ps += __shfl_xor(ps, sft);
            pd += __shfl_xor(pd, sft);
        }
        if (o == 0) { als2[v] = ps; ald2[v] = pd; }
    }
}

// ---------------------------------------------------------------------------
// conv2 aggregation: wave per node; edge-parallel coefs, then broadcast
// accumulate of g rows (two edges per iteration via wave halves).
// ---------------------------------------------------------------------------
__global__ __launch_bounds__(64) void agg2_kernel(
        const float* __restrict__ g,
        const float* __restrict__ als2, const float* __restrict__ ald2,
        const int* __restrict__ csr_src, const int* __restrict__ off,
        const int* __restrict__ deg,
        const float* __restrict__ b2, float* __restrict__ h2) {
    const int v = blockIdx.x;
    const int lane = threadIdx.x;
    const int half = lane >> 5;
    const int c = lane & 31;
    const int start = off[v];
    const int d = deg[v];
    const float ad = ald2[v];

    float m = -1e30f, zl = 0.f, acc = 0.f;

    for (int base = 0; base < d; base += 64) {
        const int j = base + lane;
        const bool act = (j < d);
        int s = act ? csr_src[start + j] : 0;
        float e = act ? (als2[s] + ad) : -1e30f;
        e = (e > 0.f) ? e : NEG_SLOPE * e;
        float rm = e;
#pragma unroll
        for (int sft = 32; sft; sft >>= 1) rm = fmaxf(rm, __shfl_xor(rm, sft));
        float nm = fmaxf(m, rm);
        float scale = __expf(m - nm);
        float w = __expf(e - nm);
        zl = zl * scale + w;
        acc *= scale;
        const int cnt = min(d - base, 64);
        for (int jj = 0; jj + half < cnt; jj += 2) {
            int idx = jj + half;
            int  sj = __shfl(s, idx);
            float wj = __shfl(w, idx);
            acc += wj * g[sj * C2 + c];
        }
        m = nm;
    }
    acc += __shfl_xor(acc, 32);                 // combine halves (per channel c)
#pragma unroll
    for (int sft = 32; sft; sft >>= 1) zl += __shfl_xor(zl, sft);
    if (lane < 32) h2[v * C2 + lane] = acc / (zl + 1e-16f) + b2[lane];
}

// ---------------------------------------------------------------------------
// link scorer: 32 lanes per candidate pair (2 pairs per wave)
// ---------------------------------------------------------------------------
__global__ __launch_bounds__(256) void score_kernel(
        const float* __restrict__ h2, const int* __restrict__ cand,
        const float* __restrict__ Ws, const float* __restrict__ bs,
        float* __restrict__ out) {
    const int gid = blockIdx.x * blockDim.x + threadIdx.x;
    const int p = gid >> 5;
    if (p >= N_CAND) return;
    const int c = threadIdx.x & 31;
    const int a = cand[2 * p], b = cand[2 * p + 1];
    float v = h2[a * C2 + c] * Ws[c] + h2[b * C2 + c] * Ws[32 + c];
#pragma unroll
    for (int sft = 16; sft; sft >>= 1) v += __shfl_xor(v, sft);
    if (c == 0) out[p] = 1.f / (1.f + __expf(-(v + bs[0])));
}

// ---------------------------------------------------------------------------
extern "C" void kernel_launch(void* const* d_in, const int* in_sizes, int n_in,
                              void* d_out, int out_size, void* d_ws, size_t ws_size,
                              hipStream_t stream) {
    const float* x        = (const float*)d_in[0];
    const int*   ei       = (const int*)  d_in[1];   // [2, N_EDGES]
    const int*   cand     = (const int*)  d_in[2];   // [N_CAND, 2]
    const float* W1       = (const float*)d_in[3];
    const float* a_src1   = (const float*)d_in[4];
    const float* a_dst1   = (const float*)d_in[5];
    const float* b1       = (const float*)d_in[6];
    const float* W2       = (const float*)d_in[7];
    const float* a_src2   = (const float*)d_in[8];
    const float* a_dst2   = (const float*)d_in[9];
    const float* b2       = (const float*)d_in[10];
    const float* Ws       = (const float*)d_in[11];
    const float* bs       = (const float*)d_in[12];
    float* out = (float*)d_out;

    // workspace carve-up
    float* h1v  = (float*)d_ws;                      // 20000*256
    float* g    = h1v  + (size_t)N_NODES * H1C1;     // 20000*32
    float* h2v  = g    + (size_t)N_NODES * C2;       // 20000*32
    float* als1 = h2v  + (size_t)N_NODES * C2;       // 20000*4
    float* ald1 = als1 + (size_t)N_NODES * 4;
    float* als2 = ald1 + (size_t)N_NODES * 4;        // 20000
    float* ald2 = als2 + N_NODES;
    float* p1   = ald2 + N_NODES;                    // 64
    int*   deg  = (int*)(p1 + 64);                   // 20000
    int*   cur  = deg  + N_NODES;
    int*   off  = cur  + N_NODES;
    int*   csr  = off  + N_NODES;                    // 340000

    (void)hipMemsetAsync(deg, 0, N_NODES * sizeof(int), stream);

    const int eb = (E_TOT + 255) / 256;
    degree_kernel <<<eb, 256, 0, stream>>>(ei, deg);
    scan_kernel   <<<1, 1024, 0, stream>>>(deg, off, cur);
    scatter_kernel<<<eb, 256, 0, stream>>>(ei, cur, csr);

    prep_kernel  <<<1, 64, 0, stream>>>(W1, a_src1, a_dst1, p1);
    alpha1_kernel<<<(N_NODES + 255) / 256, 256, 0, stream>>>(x, p1, als1, ald1);

    agg1_kernel      <<<N_NODES, 64, 0, stream>>>(x, als1, ald1, csr, off, deg, W1, b1, h1v);
    transform2_kernel<<<N_NODES, 256, 0, stream>>>(h1v, W2, a_src2, a_dst2, g, als2, ald2);
    agg2_kernel      <<<N_NODES, 64, 0, stream>>>(g, als2, ald2, csr, off, deg, b2, h2v);

    score_kernel<<<(N_CAND * 32 + 255) / 256, 256, 0, stream>>>(h2v, cand, Ws, bs, out);
}

// Round 4
// 246.166 us; speedup vs baseline: 2.0828x; 1.0597x over previous
//
#include <hip/hip_runtime.h>

// Problem constants (match reference)
#define N_NODES  20000
#define N_EDGES  320000
#define E_TOT    340000      // + self loops
#define N_CAND   200000
#define IN_DIM   7
#define H1C1     256         // 4 heads * 64
#define C2       32
#define NEG_SLOPE 0.2f
#define ALPHA_BLOCKS ((N_NODES + 255) / 256)   // 79

// ---------------------------------------------------------------------------
// build: degree histogram (all edges) + p1 + alpha1 + xpad (first 79 blocks)
// p1[sd][k][h] = sum_c W1[k, h*64+c] * a_{src/dst}1[h, c]
// ---------------------------------------------------------------------------
__global__ __launch_bounds__(256) void build_kernel(
        const int* __restrict__ ei, const float* __restrict__ x,
        const float* __restrict__ W1,
        const float* __restrict__ a_src1, const float* __restrict__ a_dst1,
        int* __restrict__ deg,
        float* __restrict__ als1, float* __restrict__ ald1,
        float* __restrict__ xpad) {
    const int bid = blockIdx.x, t = threadIdx.x;
    const int e = bid * 256 + t;
    if (e < E_TOT) {
        int dst = (e < N_EDGES) ? ei[N_EDGES + e] : (e - N_EDGES);
        atomicAdd(&deg[dst], 1);
    }
    if (bid < ALPHA_BLOCKS) {
        __shared__ float p1[56];
        __shared__ float xr[256 * IN_DIM];
        if (t < 56) {
            int sd = t / 28, rem = t % 28, k = rem >> 2, h = rem & 3;
            const float* a = sd ? a_dst1 : a_src1;
            float sum = 0.f;
            for (int c = 0; c < 64; ++c)
                sum += W1[k * H1C1 + h * 64 + c] * a[h * 64 + c];
            p1[t] = sum;   // [sd*28 + k*4 + h]
        }
        const int vbase = bid * 256;
#pragma unroll
        for (int i = 0; i < IN_DIM; ++i) {
            int idx = vbase * IN_DIM + i * 256 + t;
            if (idx < N_NODES * IN_DIM) xr[i * 256 + t] = x[idx];
        }
        __syncthreads();
        const int v = vbase + t;
        if (v < N_NODES) {
            float xs[IN_DIM];
#pragma unroll
            for (int k = 0; k < IN_DIM; ++k) xs[k] = xr[t * IN_DIM + k];
            float4 s = {0.f,0.f,0.f,0.f}, d = {0.f,0.f,0.f,0.f};
#pragma unroll
            for (int k = 0; k < IN_DIM; ++k) {
                float4 ps = *(const float4*)&p1[k * 4];
                float4 pd = *(const float4*)&p1[28 + k * 4];
                s.x += xs[k]*ps.x; s.y += xs[k]*ps.y; s.z += xs[k]*ps.z; s.w += xs[k]*ps.w;
                d.x += xs[k]*pd.x; d.y += xs[k]*pd.y; d.z += xs[k]*pd.z; d.w += xs[k]*pd.w;
            }
            *(float4*)&als1[v * 4] = s;
            *(float4*)&ald1[v * 4] = d;
            float4 xa = {xs[0], xs[1], xs[2], xs[3]};
            float4 xb = {xs[4], xs[5], xs[6], 1.0f};   // slot 7 = 1 folds z into acc
            *(float4*)&xpad[v * 8]     = xa;
            *(float4*)&xpad[v * 8 + 4] = xb;
        }
    }
}

// ---------------------------------------------------------------------------
// scan: single block exclusive prefix over degrees
// ---------------------------------------------------------------------------
__global__ __launch_bounds__(1024) void scan_kernel(const int* __restrict__ deg,
                                                    int* __restrict__ off,
                                                    int* __restrict__ cursor) {
    __shared__ int part[1024];
    const int t = threadIdx.x;
    const int per = (N_NODES + 1023) / 1024;   // 20
    const int start = t * per;
    const int end = min(start + per, N_NODES);
    int s = 0;
    for (int i = start; i < end; ++i) s += deg[i];
    part[t] = s;
    __syncthreads();
    for (int d = 1; d < 1024; d <<= 1) {
        int add = (t >= d) ? part[t - d] : 0;
        __syncthreads();
        part[t] += add;
        __syncthreads();
    }
    int run = part[t] - s;
    for (int i = start; i < end; ++i) {
        off[i] = run;
        cursor[i] = run;
        run += deg[i];
    }
}

__global__ void scatter_kernel(const int* __restrict__ ei,
                               int* __restrict__ cursor,
                               int* __restrict__ csr_src) {
    int e = blockIdx.x * blockDim.x + threadIdx.x;
    if (e >= E_TOT) return;
    int src, dst;
    if (e < N_EDGES) { src = ei[e]; dst = ei[N_EDGES + e]; }
    else             { src = dst = e - N_EDGES; }
    int pos = atomicAdd(&cursor[dst], 1);
    csr_src[pos] = src;
}

// ---------------------------------------------------------------------------
// agg1 fused: softmax-weighted x aggregation (linearity trick), W1 transform,
// bias+ELU, then g = h1@W2 + alpha2 in-block (transform2 fused via LDS).
// 256-thread blocks, one wave per node.
// ---------------------------------------------------------------------------
__global__ __launch_bounds__(256) void agg1_kernel(
        const float* __restrict__ xpad,
        const float* __restrict__ als1, const float* __restrict__ ald1,
        const int* __restrict__ csr_src, const int* __restrict__ off,
        const int* __restrict__ deg,
        const float* __restrict__ W1, const float* __restrict__ b1,
        const float* __restrict__ W2,
        const float* __restrict__ a_src2, const float* __restrict__ a_dst2,
        float* __restrict__ g, float* __restrict__ als2, float* __restrict__ ald2) {
    __shared__ float hl[4][H1C1];
    const int wid  = threadIdx.x >> 6;
    const int lane = threadIdx.x & 63;
    const int v = blockIdx.x * 4 + wid;          // grid = 5000 -> exactly 20000
    const int start = off[v];
    const int d = deg[v];
    const float4 adv = *(const float4*)&ald1[v * 4];
    const float ad[4] = {adv.x, adv.y, adv.z, adv.w};

    float acc[4][8];                             // [head][x0..x6, z]

    if (d <= 64) {
        // ---- fast path: all edges fit one wave round ----
        const bool act = lane < d;
        const int s = csr_src[start + (act ? lane : 0)];
        float4 av = *(const float4*)&als1[s * 4];
        float e[4] = {av.x + ad[0], av.y + ad[1], av.z + ad[2], av.w + ad[3]};
#pragma unroll
        for (int h = 0; h < 4; ++h) {
            e[h] = (e[h] > 0.f) ? e[h] : NEG_SLOPE * e[h];
            if (!act) e[h] = -1e30f;
        }
        float m[4], w[4];
#pragma unroll
        for (int h = 0; h < 4; ++h) {
            float rm = e[h];
#pragma unroll
            for (int sft = 32; sft; sft >>= 1) rm = fmaxf(rm, __shfl_xor(rm, sft));
            m[h] = rm;
            w[h] = __expf(e[h] - rm);            // inactive -> exp(-huge) = 0
        }
        float4 xa = *(const float4*)&xpad[s * 8];
        float4 xb = *(const float4*)&xpad[s * 8 + 4];
        const float xs[8] = {xa.x, xa.y, xa.z, xa.w, xb.x, xb.y, xb.z, xb.w};
#pragma unroll
        for (int h = 0; h < 4; ++h)
#pragma unroll
            for (int k = 0; k < 8; ++k) acc[h][k] = w[h] * xs[k];
    } else {
        // ---- slow path: online softmax over 64-edge rounds (rare) ----
        float m[4] = {-1e30f, -1e30f, -1e30f, -1e30f};
#pragma unroll
        for (int h = 0; h < 4; ++h)
#pragma unroll
            for (int k = 0; k < 8; ++k) acc[h][k] = 0.f;
        for (int base = 0; base < d; base += 64) {
            const int j = base + lane;
            const bool act = (j < d);
            const int s = csr_src[start + (act ? j : 0)];
            float4 av = *(const float4*)&als1[s * 4];
            float e[4] = {av.x + ad[0], av.y + ad[1], av.z + ad[2], av.w + ad[3]};
#pragma unroll
            for (int h = 0; h < 4; ++h) {
                e[h] = (e[h] > 0.f) ? e[h] : NEG_SLOPE * e[h];
                if (!act) e[h] = -1e30f;
            }
            float4 xa = *(const float4*)&xpad[s * 8];
            float4 xb = *(const float4*)&xpad[s * 8 + 4];
            const float xs[8] = {xa.x, xa.y, xa.z, xa.w, xb.x, xb.y, xb.z, xb.w};
#pragma unroll
            for (int h = 0; h < 4; ++h) {
                float rm = e[h];
#pragma unroll
                for (int sft = 32; sft; sft >>= 1) rm = fmaxf(rm, __shfl_xor(rm, sft));
                float nm = fmaxf(m[h], rm);
                float scale = __expf(m[h] - nm);
                float w = __expf(e[h] - nm);
#pragma unroll
                for (int k = 0; k < 8; ++k)
                    acc[h][k] = acc[h][k] * scale + w * xs[k];
                m[h] = nm;
            }
        }
    }
    // allreduce the 32 accumulators across the wave
#pragma unroll
    for (int h = 0; h < 4; ++h)
#pragma unroll
        for (int k = 0; k < 8; ++k)
#pragma unroll
            for (int sft = 32; sft; sft >>= 1)
                acc[h][k] += __shfl_xor(acc[h][k], sft);

    // h1 row: out[h][lane] = (xagg/z)@W1 + b1, ELU; stage to LDS
#pragma unroll
    for (int h = 0; h < 4; ++h) {
        const float inv = 1.f / (acc[h][7] + 1e-16f);
        float o = 0.f;
#pragma unroll
        for (int k = 0; k < IN_DIM; ++k)
            o += acc[h][k] * W1[k * H1C1 + h * 64 + lane];
        o = o * inv + b1[h * 64 + lane];
        hl[wid][h * 64 + lane] = (o > 0.f) ? o : (__expf(o) - 1.f);
    }
    __syncthreads();

    // g = h1 @ W2 : output o = lane&31; halves split the 256-long k range
    const int o = lane & 31, half = lane >> 5;
    const float* hrow = hl[wid];
    float ga0 = 0.f, ga1 = 0.f, ga2 = 0.f, ga3 = 0.f;
    const int kb = half * 128;
#pragma unroll 8
    for (int k = 0; k < 128; k += 4) {
        ga0 += hrow[kb + k]     * W2[(kb + k)     * C2 + o];
        ga1 += hrow[kb + k + 1] * W2[(kb + k + 1) * C2 + o];
        ga2 += hrow[kb + k + 2] * W2[(kb + k + 2) * C2 + o];
        ga3 += hrow[kb + k + 3] * W2[(kb + k + 3) * C2 + o];
    }
    float gv = (ga0 + ga1) + (ga2 + ga3);
    gv += __shfl_xor(gv, 32);                    // combine k-halves

    // alpha2 from g row (both halves hold gv; butterfly width 32)
    float ps = gv * a_src2[o];
    float pd = gv * a_dst2[o];
#pragma unroll
    for (int sft = 16; sft; sft >>= 1) {
        ps += __shfl_xor(ps, sft);
        pd += __shfl_xor(pd, sft);
    }
    if (lane == 0) { als2[v] = ps; ald2[v] = pd; }
    if (lane < 32) g[v * C2 + o] = gv;
}

// ---------------------------------------------------------------------------
// conv2 aggregation: 256-thread blocks, wave per node; edge-parallel coefs,
// then broadcast accumulate of g rows (two edges per iteration via halves).
// ---------------------------------------------------------------------------
__global__ __launch_bounds__(256) void agg2_kernel(
        const float* __restrict__ g,
        const float* __restrict__ als2, const float* __restrict__ ald2,
        const int* __restrict__ csr_src, const int* __restrict__ off,
        const int* __restrict__ deg,
        const float* __restrict__ b2, float* __restrict__ h2) {
    const int wid  = threadIdx.x >> 6;
    const int lane = threadIdx.x & 63;
    const int v = blockIdx.x * 4 + wid;
    const int half = lane >> 5;
    const int c = lane & 31;
    const int start = off[v];
    const int d = deg[v];
    const float ad = ald2[v];

    float m = -1e30f, zl = 0.f, acc = 0.f;

    for (int base = 0; base < d; base += 64) {
        const int j = base + lane;
        const bool act = (j < d);
        int s = act ? csr_src[start + j] : 0;
        float e = act ? (als2[s] + ad) : -1e30f;
        e = (e > 0.f) ? e : NEG_SLOPE * e;
        float rm = e;
#pragma unroll
        for (int sft = 32; sft; sft >>= 1) rm = fmaxf(rm, __shfl_xor(rm, sft));
        float nm = fmaxf(m, rm);
        float scale = __expf(m - nm);
        float w = __expf(e - nm);
        zl = zl * scale + w;
        acc *= scale;
        const int cnt = min(d - base, 64);
        for (int jj = 0; jj + half < cnt; jj += 2) {
            int idx = jj + half;
            int  sj = __shfl(s, idx);
            float wj = __shfl(w, idx);
            acc += wj * g[sj * C2 + c];
        }
        m = nm;
    }
    acc += __shfl_xor(acc, 32);                 // combine halves
#pragma unroll
    for (int sft = 32; sft; sft >>= 1) zl += __shfl_xor(zl, sft);
    if (lane < 32) h2[v * C2 + lane] = acc / (zl + 1e-16f) + b2[lane];
}

// ---------------------------------------------------------------------------
// link scorer: 32 lanes per candidate pair (2 pairs per wave)
// ---------------------------------------------------------------------------
__global__ __launch_bounds__(256) void score_kernel(
        const float* __restrict__ h2, const int* __restrict__ cand,
        const float* __restrict__ Ws, const float* __restrict__ bs,
        float* __restrict__ out) {
    const int gid = blockIdx.x * blockDim.x + threadIdx.x;
    const int p = gid >> 5;
    if (p >= N_CAND) return;
    const int c = threadIdx.x & 31;
    const int a = cand[2 * p], b = cand[2 * p + 1];
    float v = h2[a * C2 + c] * Ws[c] + h2[b * C2 + c] * Ws[32 + c];
#pragma unroll
    for (int sft = 16; sft; sft >>= 1) v += __shfl_xor(v, sft);
    if (c == 0) out[p] = 1.f / (1.f + __expf(-(v + bs[0])));
}

// ---------------------------------------------------------------------------
extern "C" void kernel_launch(void* const* d_in, const int* in_sizes, int n_in,
                              void* d_out, int out_size, void* d_ws, size_t ws_size,
                              hipStream_t stream) {
    const float* x        = (const float*)d_in[0];
    const int*   ei       = (const int*)  d_in[1];
    const int*   cand     = (const int*)  d_in[2];
    const float* W1       = (const float*)d_in[3];
    const float* a_src1   = (const float*)d_in[4];
    const float* a_dst1   = (const float*)d_in[5];
    const float* b1       = (const float*)d_in[6];
    const float* W2       = (const float*)d_in[7];
    const float* a_src2   = (const float*)d_in[8];
    const float* a_dst2   = (const float*)d_in[9];
    const float* b2       = (const float*)d_in[10];
    const float* Ws       = (const float*)d_in[11];
    const float* bs       = (const float*)d_in[12];
    float* out = (float*)d_out;

    // workspace carve-up (floats/ints, 4B each)
    float* xpad = (float*)d_ws;                      // 20000*8
    float* g    = xpad + (size_t)N_NODES * 8;        // 20000*32
    float* h2v  = g    + (size_t)N_NODES * C2;       // 20000*32
    float* als1 = h2v  + (size_t)N_NODES * C2;       // 20000*4
    float* ald1 = als1 + (size_t)N_NODES * 4;
    float* als2 = ald1 + (size_t)N_NODES * 4;        // 20000
    float* ald2 = als2 + N_NODES;
    int*   deg  = (int*)(ald2 + N_NODES);            // 20000
    int*   cur  = deg  + N_NODES;
    int*   off  = cur  + N_NODES;
    int*   csr  = off  + N_NODES;                    // 340000

    (void)hipMemsetAsync(deg, 0, N_NODES * sizeof(int), stream);

    const int eb = (E_TOT + 255) / 256;
    build_kernel  <<<eb, 256, 0, stream>>>(ei, x, W1, a_src1, a_dst1,
                                           deg, als1, ald1, xpad);
    scan_kernel   <<<1, 1024, 0, stream>>>(deg, off, cur);
    scatter_kernel<<<eb, 256, 0, stream>>>(ei, cur, csr);

    agg1_kernel<<<N_NODES / 4, 256, 0, stream>>>(xpad, als1, ald1, csr, off, deg,
                                                 W1, b1, W2, a_src2, a_dst2,
                                                 g, als2, ald2);
    agg2_kernel<<<N_NODES / 4, 256, 0, stream>>>(g, als2, ald2, csr, off, deg,
                                                 b2, h2v);

    score_kernel<<<(N_CAND * 32 + 255) / 256, 256, 0, stream>>>(h2v, cand, Ws, bs, out);
}

// Round 5
// 181.891 us; speedup vs baseline: 2.8188x; 1.3534x over previous
//
#include <hip/hip_runtime.h>

// Problem constants (match reference)
#define N_NODES  20000
#define N_EDGES  320000
#define E_TOT    340000      // + self loops
#define N_CAND   200000
#define IN_DIM   7
#define H1C1     256         // 4 heads * 64
#define C2       32
#define NEG_SLOPE 0.2f
#define ALPHA_BLOCKS ((N_NODES + 255) / 256)   // 79
#define QPREP_BLOCK 1000                        // block that builds the q-vectors

// ---------------------------------------------------------------------------
// build: degree histogram (all 340k edges) + p1/alpha1/xpad (blocks 0..78)
//        + q-vector prep (block 1000):  q[r] = W2 @ {a_src2,a_dst2,Ws0,Ws1}
// ---------------------------------------------------------------------------
__global__ __launch_bounds__(256) void build_kernel(
        const int* __restrict__ ei, const float* __restrict__ x,
        const float* __restrict__ W1,
        const float* __restrict__ a_src1, const float* __restrict__ a_dst1,
        const float* __restrict__ W2,
        const float* __restrict__ a_src2, const float* __restrict__ a_dst2,
        const float* __restrict__ Ws, const float* __restrict__ b2,
        int* __restrict__ deg,
        float* __restrict__ als1, float* __restrict__ ald1,
        float* __restrict__ xpad, float* __restrict__ q) {
    const int bid = blockIdx.x, t = threadIdx.x;
    const int e = bid * 256 + t;
    if (e < E_TOT) {
        int dst = (e < N_EDGES) ? ei[N_EDGES + e] : (e - N_EDGES);
        atomicAdd(&deg[dst], 1);
    }
    if (bid < ALPHA_BLOCKS) {
        __shared__ float p1[56];
        __shared__ float xr[256 * IN_DIM];
        if (t < 56) {
            int sd = t / 28, rem = t % 28, k = rem >> 2, h = rem & 3;
            const float* a = sd ? a_dst1 : a_src1;
            float sum = 0.f;
            for (int c = 0; c < 64; ++c)
                sum += W1[k * H1C1 + h * 64 + c] * a[h * 64 + c];
            p1[t] = sum;   // [sd*28 + k*4 + h]
        }
        const int vbase = bid * 256;
#pragma unroll
        for (int i = 0; i < IN_DIM; ++i) {
            int idx = vbase * IN_DIM + i * 256 + t;
            if (idx < N_NODES * IN_DIM) xr[i * 256 + t] = x[idx];
        }
        __syncthreads();
        const int v = vbase + t;
        if (v < N_NODES) {
            float xs[IN_DIM];
#pragma unroll
            for (int k = 0; k < IN_DIM; ++k) xs[k] = xr[t * IN_DIM + k];
            float4 s = {0.f,0.f,0.f,0.f}, d = {0.f,0.f,0.f,0.f};
#pragma unroll
            for (int k = 0; k < IN_DIM; ++k) {
                float4 ps = *(const float4*)&p1[k * 4];
                float4 pd = *(const float4*)&p1[28 + k * 4];
                s.x += xs[k]*ps.x; s.y += xs[k]*ps.y; s.z += xs[k]*ps.z; s.w += xs[k]*ps.w;
                d.x += xs[k]*pd.x; d.y += xs[k]*pd.y; d.z += xs[k]*pd.z; d.w += xs[k]*pd.w;
            }
            *(float4*)&als1[v * 4] = s;
            *(float4*)&ald1[v * 4] = d;
            float4 xa = {xs[0], xs[1], xs[2], xs[3]};
            float4 xb = {xs[4], xs[5], xs[6], 1.0f};   // slot 7 = 1 folds z into acc
            *(float4*)&xpad[v * 8]     = xa;
            *(float4*)&xpad[v * 8 + 4] = xb;
        }
    } else if (bid == QPREP_BLOCK) {
        // q[r*256 + i] = sum_c W2[i*32+c] * avec_r[c]
#pragma unroll
        for (int r = 0; r < 4; ++r) {
            const float* av = (r == 0) ? a_src2 : (r == 1) ? a_dst2
                              : (r == 2) ? Ws : (Ws + C2);
            float s = 0.f;
#pragma unroll 8
            for (int c = 0; c < C2; ++c) s += W2[t * C2 + c] * av[c];
            q[r * 256 + t] = s;
        }
        if (t == 0) {
            float cu = 0.f, cw = 0.f;
            for (int c = 0; c < C2; ++c) { cu += b2[c] * Ws[c]; cw += b2[c] * Ws[C2 + c]; }
            q[1024] = cu; q[1025] = cw;
        }
    }
}

// ---------------------------------------------------------------------------
// scan: single block exclusive prefix over degrees
// ---------------------------------------------------------------------------
__global__ __launch_bounds__(1024) void scan_kernel(const int* __restrict__ deg,
                                                    int* __restrict__ off,
                                                    int* __restrict__ cursor) {
    __shared__ int part[1024];
    const int t = threadIdx.x;
    const int per = (N_NODES + 1023) / 1024;   // 20
    const int start = t * per;
    const int end = min(start + per, N_NODES);
    int s = 0;
    for (int i = start; i < end; ++i) s += deg[i];
    part[t] = s;
    __syncthreads();
    for (int d = 1; d < 1024; d <<= 1) {
        int add = (t >= d) ? part[t - d] : 0;
        __syncthreads();
        part[t] += add;
        __syncthreads();
    }
    int run = part[t] - s;
    for (int i = start; i < end; ++i) {
        off[i] = run;
        cursor[i] = run;
        run += deg[i];
    }
}

__global__ void scatter_kernel(const int* __restrict__ ei,
                               int* __restrict__ cursor,
                               int* __restrict__ csr_src) {
    int e = blockIdx.x * blockDim.x + threadIdx.x;
    if (e >= E_TOT) return;
    int src, dst;
    if (e < N_EDGES) { src = ei[e]; dst = ei[N_EDGES + e]; }
    else             { src = dst = e - N_EDGES; }
    int pos = atomicAdd(&cursor[dst], 1);
    csr_src[pos] = src;
}

// ---------------------------------------------------------------------------
// agg1: head-per-lane-class (lane = head*16 + slot). Online softmax over
// 16-edge rounds; linearity trick aggregates padded x (8 components, z in
// slot 7); epilogue applies W1 column, bias+ELU, then 4 q-projections
// (als2, ald2, gu, gw) -> n2[v] float4. No LDS, no syncthreads.
// ---------------------------------------------------------------------------
__global__ __launch_bounds__(256) void agg1_kernel(
        const float* __restrict__ xpad,
        const float* __restrict__ als1, const float* __restrict__ ald1,
        const int* __restrict__ csr, const int* __restrict__ off,
        const int* __restrict__ deg,
        const float* __restrict__ W1, const float* __restrict__ b1,
        const float* __restrict__ q,
        float* __restrict__ n2) {
    const int wid  = threadIdx.x >> 6;
    const int lane = threadIdx.x & 63;
    const int head = lane >> 4;          // 0..3
    const int slot = lane & 15;          // 0..15
    const int v = blockIdx.x * 4 + wid;  // grid 5000 -> exactly 20000
    const int start = off[v];
    const int d = deg[v];
    const float ad = ald1[v * 4 + head];

    float m = -1e30f;
    float acc[8] = {0.f,0.f,0.f,0.f,0.f,0.f,0.f,0.f};

    for (int base = 0; base < d; base += 16) {
        const int j = base + slot;
        const bool act = (j < d);
        const int s = csr[start + (act ? j : 0)];
        float e = als1[s * 4 + head] + ad;
        e = (e > 0.f) ? e : NEG_SLOPE * e;
        if (!act) e = -1e30f;
        // max over the 16-lane head class
        float rm = e;
        rm = fmaxf(rm, __shfl_xor(rm, 1));
        rm = fmaxf(rm, __shfl_xor(rm, 2));
        rm = fmaxf(rm, __shfl_xor(rm, 4));
        rm = fmaxf(rm, __shfl_xor(rm, 8));
        const float nm = fmaxf(m, rm);
        const float sc = __expf(m - nm);   // first round: exp(-huge)=0, accs are 0
        const float w  = __expf(e - nm);   // inactive lanes -> 0
        const float4 xa = *(const float4*)&xpad[s * 8];
        const float4 xb = *(const float4*)&xpad[s * 8 + 4];
        acc[0] = acc[0]*sc + w*xa.x; acc[1] = acc[1]*sc + w*xa.y;
        acc[2] = acc[2]*sc + w*xa.z; acc[3] = acc[3]*sc + w*xa.w;
        acc[4] = acc[4]*sc + w*xb.x; acc[5] = acc[5]*sc + w*xb.y;
        acc[6] = acc[6]*sc + w*xb.z; acc[7] = acc[7]*sc + w*xb.w;
        m = nm;
    }
    // sum-reduce the 8 accumulators over the 16-lane class (broadcast result)
#pragma unroll
    for (int k = 0; k < 8; ++k) {
        acc[k] += __shfl_xor(acc[k], 1);
        acc[k] += __shfl_xor(acc[k], 2);
        acc[k] += __shfl_xor(acc[k], 4);
        acc[k] += __shfl_xor(acc[k], 8);
    }
    const float inv = 1.f / (acc[7] + 1e-16f);
    float sa[IN_DIM];
#pragma unroll
    for (int k = 0; k < IN_DIM; ++k) sa[k] = acc[k] * inv;

    // h1 channels cb+16j for this lane; then 4 q-projections
    const int cb = head * 64 + slot;
    float ds = 0.f, dd = 0.f, du = 0.f, dw = 0.f;
#pragma unroll
    for (int jj = 0; jj < 4; ++jj) {
        const int c = cb + 16 * jj;
        float o = b1[c];
#pragma unroll
        for (int k = 0; k < IN_DIM; ++k)
            o += sa[k] * W1[k * H1C1 + c];
        const float h1v = (o > 0.f) ? o : (__expf(o) - 1.f);
        ds += h1v * q[c];
        dd += h1v * q[256 + c];
        du += h1v * q[512 + c];
        dw += h1v * q[768 + c];
    }
#pragma unroll
    for (int sft = 32; sft; sft >>= 1) {
        ds += __shfl_xor(ds, sft);
        dd += __shfl_xor(dd, sft);
        du += __shfl_xor(du, sft);
        dw += __shfl_xor(dw, sft);
    }
    if (lane == 0) {
        float4 r = {ds, dd, du, dw};
        *(float4*)&n2[v * 4] = r;
    }
}

// ---------------------------------------------------------------------------
// agg2 (+ scorer projections): per edge one float4 gather (als2,ald2,gu,gw);
// online softmax over 64-edge rounds; outputs u[v], w[v] scalars.
// ---------------------------------------------------------------------------
__global__ __launch_bounds__(256) void agg2_kernel(
        const float* __restrict__ n2,
        const int* __restrict__ csr, const int* __restrict__ off,
        const int* __restrict__ deg,
        const float* __restrict__ q,
        float* __restrict__ uu, float* __restrict__ ww) {
    const int wid  = threadIdx.x >> 6;
    const int lane = threadIdx.x & 63;
    const int v = blockIdx.x * 4 + wid;
    const int start = off[v];
    const int d = deg[v];
    const float ad = n2[v * 4 + 1];

    float m = -1e30f, sw = 0.f, sgu = 0.f, sgw = 0.f;
    for (int base = 0; base < d; base += 64) {
        const int j = base + lane;
        const bool act = (j < d);
        const int s = csr[start + (act ? j : 0)];
        const float4 r = *(const float4*)&n2[s * 4];
        float e = r.x + ad;
        e = (e > 0.f) ? e : NEG_SLOPE * e;
        if (!act) e = -1e30f;
        float rm = e;
#pragma unroll
        for (int sft = 32; sft; sft >>= 1) rm = fmaxf(rm, __shfl_xor(rm, sft));
        const float nm = fmaxf(m, rm);
        const float sc = __expf(m - nm);
        const float w  = __expf(e - nm);
        sw  = sw  * sc + w;
        sgu = sgu * sc + w * r.z;
        sgw = sgw * sc + w * r.w;
        m = nm;
    }
#pragma unroll
    for (int sft = 32; sft; sft >>= 1) {
        sw  += __shfl_xor(sw, sft);
        sgu += __shfl_xor(sgu, sft);
        sgw += __shfl_xor(sgw, sft);
    }
    if (lane == 0) {
        const float inv = 1.f / (sw + 1e-16f);
        uu[v] = sgu * inv + q[1024];
        ww[v] = sgw * inv + q[1025];
    }
}

// ---------------------------------------------------------------------------
// link scorer: 1 thread per candidate pair
// ---------------------------------------------------------------------------
__global__ __launch_bounds__(256) void score_kernel(
        const float* __restrict__ uu, const float* __restrict__ ww,
        const int* __restrict__ cand, const float* __restrict__ bs,
        float* __restrict__ out) {
    const int p = blockIdx.x * 256 + threadIdx.x;
    if (p >= N_CAND) return;
    const int2 ab = ((const int2*)cand)[p];
    const float s = uu[ab.x] + ww[ab.y] + bs[0];
    out[p] = 1.f / (1.f + __expf(-s));
}

// ---------------------------------------------------------------------------
extern "C" void kernel_launch(void* const* d_in, const int* in_sizes, int n_in,
                              void* d_out, int out_size, void* d_ws, size_t ws_size,
                              hipStream_t stream) {
    const float* x        = (const float*)d_in[0];
    const int*   ei       = (const int*)  d_in[1];
    const int*   cand     = (const int*)  d_in[2];
    const float* W1       = (const float*)d_in[3];
    const float* a_src1   = (const float*)d_in[4];
    const float* a_dst1   = (const float*)d_in[5];
    const float* b1       = (const float*)d_in[6];
    const float* W2       = (const float*)d_in[7];
    const float* a_src2   = (const float*)d_in[8];
    const float* a_dst2   = (const float*)d_in[9];
    const float* b2       = (const float*)d_in[10];
    const float* Ws       = (const float*)d_in[11];
    const float* bs       = (const float*)d_in[12];
    float* out = (float*)d_out;

    // workspace carve-up (4B elements)
    float* xpad = (float*)d_ws;                      // 20000*8
    float* n2   = xpad + (size_t)N_NODES * 8;        // 20000*4
    float* als1 = n2   + (size_t)N_NODES * 4;        // 20000*4
    float* ald1 = als1 + (size_t)N_NODES * 4;        // 20000*4
    float* uu   = ald1 + (size_t)N_NODES * 4;        // 20000
    float* ww   = uu   + N_NODES;                    // 20000
    float* q    = ww   + N_NODES;                    // 1026 (pad 1028)
    int*   deg  = (int*)(q + 1028);                  // 20000
    int*   cur  = deg  + N_NODES;
    int*   off  = cur  + N_NODES;
    int*   csr  = off  + N_NODES;                    // 340000

    (void)hipMemsetAsync(deg, 0, N_NODES * sizeof(int), stream);

    const int eb = (E_TOT + 255) / 256;              // 1329
    build_kernel  <<<eb, 256, 0, stream>>>(ei, x, W1, a_src1, a_dst1,
                                           W2, a_src2, a_dst2, Ws, b2,
                                           deg, als1, ald1, xpad, q);
    scan_kernel   <<<1, 1024, 0, stream>>>(deg, off, cur);
    scatter_kernel<<<eb, 256, 0, stream>>>(ei, cur, csr);

    agg1_kernel<<<N_NODES / 4, 256, 0, stream>>>(xpad, als1, ald1, csr, off, deg,
                                                 W1, b1, q, n2);
    agg2_kernel<<<N_NODES / 4, 256, 0, stream>>>(n2, csr, off, deg, q, uu, ww);

    score_kernel<<<(N_CAND + 255) / 256, 256, 0, stream>>>(uu, ww, cand, bs, out);
}